// Round 11
// baseline (280.231 us; speedup 1.0000x reference)
//
#include <hip/hip_runtime.h>
#include <hip/hip_bf16.h>
#include <cstdint>
#include <cstddef>

#define B_ 16
#define TX_ 256
#define TY_ 2048
#define C_ 80
#define H_ 256
#define NEG_ -1e9f
#define NEG_I (int)0xCE6E6B28   // bit pattern of -1e9f

// one backtrace step at column-in-chunk jb from row ii, using window pair W
// (rows 8p..8p+7) with fallback Wl (rows 8p-8..8p-1).
// Diag bit layout (4 independent carry-push chains in fwd): within each
// 32-bit word (4 rows), row r = byte r; column jb at bit (7-jb).
#define BT_STEP(JB)                                                           \
    {                                                                         \
        unsigned bit = ((unsigned)(W >> (((ii & 7) << 3)                      \
                                         | (7 - (JB)))) & 1u)                 \
                     & (unsigned)(ii > 0);                                    \
        ii -= (int)bit;                                                       \
        W = (bit && ((ii & 7) == 7)) ? Wl : W;                                \
    }

// ---------------------------------------------------------------------------
// Kernel 1: logp — now writes ONLY logp_t (the MAS input). The dense
// logp_out [B,Tx,Ty] is produced by the transpose-copy blocks riding in
// mas_fwd's shadow (240 idle CUs during the 78us scan).
// ---------------------------------------------------------------------------
__global__ __launch_bounds__(256) void logp_kernel(
    const float* __restrict__ mu, const float* __restrict__ ls,
    const float* __restrict__ y, float* __restrict__ logp_t)
{
    __shared__ float2 coef[16 * 80];
    __shared__ float  aux[16 * 80];
    __shared__ float  Kx[16];
    __shared__ float  yt[16 * 1028];

    const int tid = threadIdx.x;
    const int t0 = blockIdx.x * 1024;
    const int x0 = blockIdx.y * 16;
    const int b  = blockIdx.z;

    for (int i = tid; i < 16 * 80; i += 256) {
        int c = i >> 4, x = i & 15;
        float m = mu[(size_t)(b * C_ + c) * TX_ + x0 + x];
        float l = ls[(size_t)(b * C_ + c) * TX_ + x0 + x];
        float w = __expf(-2.f * l);
        coef[x * 80 + c] = make_float2(w, -2.f * m * w);
        aux[x * 80 + c]  = fmaf(m * m, w, l);
    }
    __syncthreads();
    if (tid < 16) {
        float s = 0.f;
        for (int c = 0; c < C_; ++c) s += aux[tid * 80 + c];
        Kx[tid] = -0.5f * s / (float)C_;
    }

    float acc[16][4];
#pragma unroll
    for (int x = 0; x < 16; ++x)
#pragma unroll
        for (int r = 0; r < 4; ++r) acc[x][r] = 0.f;

    const float4* y4 = (const float4*)y;
    for (int c0 = 0; c0 < C_; c0 += 16) {
        __syncthreads();
        for (int it = 0; it < 16; ++it) {
            int f = tid + it * 256;
            int t = f >> 2, k = f & 3;
            float4 v = y4[(size_t)(b * TY_ + t0 + t) * 20 + (c0 >> 2) + k];
            yt[(4 * k + 0) * 1028 + t] = v.x;
            yt[(4 * k + 1) * 1028 + t] = v.y;
            yt[(4 * k + 2) * 1028 + t] = v.z;
            yt[(4 * k + 3) * 1028 + t] = v.w;
        }
        __syncthreads();
        for (int cl = 0; cl < 16; ++cl) {
            const float4 yv = *reinterpret_cast<const float4*>(&yt[cl * 1028 + 4 * tid]);
            float4 y2 = make_float4(yv.x * yv.x, yv.y * yv.y, yv.z * yv.z, yv.w * yv.w);
#pragma unroll
            for (int x = 0; x < 16; ++x) {
                float2 f2 = coef[x * 80 + c0 + cl];
                acc[x][0] = fmaf(y2.x, f2.x, fmaf(yv.x, f2.y, acc[x][0]));
                acc[x][1] = fmaf(y2.y, f2.x, fmaf(yv.y, f2.y, acc[x][1]));
                acc[x][2] = fmaf(y2.z, f2.x, fmaf(yv.z, f2.y, acc[x][2]));
                acc[x][3] = fmaf(y2.w, f2.x, fmaf(yv.w, f2.y, acc[x][3]));
            }
        }
    }

#pragma unroll
    for (int x = 0; x < 16; ++x) {
        float kx = Kx[x];
#pragma unroll
        for (int r = 0; r < 4; ++r) acc[x][r] = fmaf(acc[x][r], -0.5f / (float)C_, kx);
    }
#pragma unroll
    for (int r = 0; r < 4; ++r) {
#pragma unroll
        for (int q = 0; q < 4; ++q) {
            float4 out = make_float4(acc[4 * q + 0][r], acc[4 * q + 1][r],
                                     acc[4 * q + 2][r], acc[4 * q + 3][r]);
            *reinterpret_cast<float4*>(
                &logp_t[(size_t)(b * TY_ + t0 + 4 * tid + r) * TX_ + x0 + 4 * q]) = out;
        }
    }
}

// ---------------------------------------------------------------------------
// Kernel 2a: MAS forward (R4-VERIFIED single-wave asm scan, s_setprio 3)
// + SHADOW TRANSPOSE-COPY: blocks 16..271 copy logp_t [B,Ty,Tx] ->
// logp_out [B,Tx,Ty] via 64x64 LDS tiles on the idle CUs, hidden under the
// 78us scan. Single kernel => stream-ordered before mas_tab (no races).
// ---------------------------------------------------------------------------
#define PROQ(A, Bq, Cq, Dq) \
    "global_load_dwordx4 " A ", %[vo], %[sb]\n\t" \
    "global_load_dwordx4 " Bq ", %[vo], %[sb] offset:0x400\n\t" \
    "global_load_dwordx4 " Cq ", %[vo], %[sb] offset:0x800\n\t" \
    "global_load_dwordx4 " Dq ", %[vo], %[sb] offset:0xC00\n\t" \
    "v_add_u32 %[vo], 0x1000, %[vo]\n\t"

#define ADDVO "v_add_u32 %[vo], 0x1000, %[vo]\n\t"

#define COLN(RQ, R0, R1, R2, R3, SHU, SHD, OFF) \
    "v_cmp_gt_f32 vcc, " SHU ", %[v0]\n\t" \
    "v_cmp_gt_f32 s[20:21], %[v0], %[v1]\n\t" \
    "v_cmp_gt_f32 s[22:23], %[v1], %[v2]\n\t" \
    "v_cmp_gt_f32 s[24:25], %[v2], %[v3]\n\t" \
    "v_max_f32 %[v3], %[v2], %[v3]\n\t" \
    "v_max_f32 %[v2], %[v1], %[v2]\n\t" \
    "v_add_f32 %[v3], " R3 ", %[v3]\n\t" \
    "v_max_f32 %[v1], %[v0], %[v1]\n\t" \
    "v_max_f32 %[v0], " SHU ", %[v0]\n\t" \
    "v_mov_b32_dpp " SHD ", %[v3] wave_shr:1 row_mask:0xf bank_mask:0xf\n\t" \
    "v_add_f32 %[v2], " R2 ", %[v2]\n\t" \
    "v_add_f32 %[v1], " R1 ", %[v1]\n\t" \
    "v_add_f32 %[v0], " R0 ", %[v0]\n\t" \
    "v_addc_co_u32 %[a0], vcc, %[a0], %[a0], vcc\n\t" \
    "v_addc_co_u32 %[a1], s[20:21], %[a1], %[a1], s[20:21]\n\t" \
    "v_addc_co_u32 %[a2], s[22:23], %[a2], %[a2], s[22:23]\n\t" \
    "v_addc_co_u32 %[a3], s[24:25], %[a3], %[a3], s[24:25]\n\t" \
    "global_load_dwordx4 " RQ ", %[vo], %[sb] offset:" OFF "\n\t"

#define STOREBLK(OFFD) \
    "v_lshl_or_b32 v29, %[a1], 8, %[a0]\n\t" \
    "v_lshl_or_b32 v29, %[a2], 16, v29\n\t" \
    "v_lshl_or_b32 v29, %[a3], 24, v29\n\t" \
    "global_store_dword %[df], v29, %[db] offset:" OFFD "\n\t" \
    "v_mov_b32 %[a0], 0\n\t" \
    "v_mov_b32 %[a1], 0\n\t" \
    "v_mov_b32 %[a2], 0\n\t" \
    "v_mov_b32 %[a3], 0\n\t"

#define WAITG "s_waitcnt vmcnt(24)\n\t"

__global__ __launch_bounds__(256, 1) void mas_fwd_kernel(
    const float* __restrict__ logp_t, unsigned int* __restrict__ diag_g,
    float* __restrict__ logp_out)
{
    __shared__ float tile[64][65];   // copy-path transpose tile (16.6 KB)
    const int tid = threadIdx.x;

    if (blockIdx.x >= 16) {
        // ---- shadow transpose-copy: 256 blocks, 8 tiles each ----
        const int cb = blockIdx.x - 16;     // 0..255
        const int b  = cb >> 4;             // batch
        const int s  = cb & 15;             // segment (8 tiles of 128)
        const int wv = tid >> 6, ln = tid & 63;
        for (int ti = 0; ti < 8; ++ti) {
            int tile_id = s * 8 + ti;       // 0..127
            int x0 = (tile_id & 3) * 64;
            int t0 = (tile_id >> 2) * 64;
            for (int r = wv; r < 64; r += 4)
                tile[r][ln] = logp_t[((size_t)b * TY_ + t0 + r) * TX_ + x0 + ln];
            __syncthreads();
            for (int r = wv; r < 64; r += 4)
                logp_out[((size_t)b * TX_ + x0 + r) * TY_ + t0 + ln] = tile[ln][r];
            __syncthreads();
        }
        return;
    }
    if (tid >= 64) return;                  // scan path: wave 0 only

    const int lane = tid;
    const int b = blockIdx.x;

    uint64_t sb = (uint64_t)(logp_t + (size_t)b * TY_ * TX_);
    uint64_t db = (uint64_t)(diag_g + (size_t)b * (TY_ / 8) * 64);
    unsigned vo = (unsigned)(lane * 16);   // voffset into logp_t (bytes)
    unsigned df = (unsigned)(lane * 4);    // voffset into diag (bytes)

    float v0 = (lane == 0) ? 0.f : NEG_, v1 = NEG_, v2 = NEG_, v3 = NEG_;
    unsigned a0 = 0, a1 = 0, a2 = 0, a3 = 0;

    asm volatile(
        "s_setprio 3\n\t"                  // protect scan wave from copy waves
        "v_mov_b32 v28, 0xce6e6b28\n\t"
        "v_mov_b32 v30, 0xce6e6b28\n\t"
        PROQ("v[32:35]",   "v[36:39]",   "v[40:43]",   "v[44:47]")
        PROQ("v[48:51]",   "v[52:55]",   "v[56:59]",   "v[60:63]")
        PROQ("v[64:67]",   "v[68:71]",   "v[72:75]",   "v[76:79]")
        PROQ("v[80:83]",   "v[84:87]",   "v[88:91]",   "v[92:95]")
        PROQ("v[96:99]",   "v[100:103]", "v[104:107]", "v[108:111]")
        PROQ("v[112:115]", "v[116:119]", "v[120:123]", "v[124:127]")
        PROQ("v[128:131]", "v[132:135]", "v[136:139]", "v[140:143]")
        PROQ("v[144:147]", "v[148:151]", "v[152:155]", "v[156:159]")
        "s_mov_b32 s26, 64\n\t"
        "Lmas_%=:\n\t"
        WAITG
        COLN("v[32:35]", "v32", "v33", "v34", "v35", "v28", "v30", "0")
        COLN("v[36:39]", "v36", "v37", "v38", "v39", "v30", "v28", "0x400")
        COLN("v[40:43]", "v40", "v41", "v42", "v43", "v28", "v30", "0x800")
        COLN("v[44:47]", "v44", "v45", "v46", "v47", "v30", "v28", "0xC00")
        ADDVO
        COLN("v[48:51]", "v48", "v49", "v50", "v51", "v28", "v30", "0")
        COLN("v[52:55]", "v52", "v53", "v54", "v55", "v30", "v28", "0x400")
        COLN("v[56:59]", "v56", "v57", "v58", "v59", "v28", "v30", "0x800")
        COLN("v[60:63]", "v60", "v61", "v62", "v63", "v30", "v28", "0xC00")
        ADDVO
        STOREBLK("0")
        WAITG
        COLN("v[64:67]", "v64", "v65", "v66", "v67", "v28", "v30", "0")
        COLN("v[68:71]", "v68", "v69", "v70", "v71", "v30", "v28", "0x400")
        COLN("v[72:75]", "v72", "v73", "v74", "v75", "v28", "v30", "0x800")
        COLN("v[76:79]", "v76", "v77", "v78", "v79", "v30", "v28", "0xC00")
        ADDVO
        COLN("v[80:83]", "v80", "v81", "v82", "v83", "v28", "v30", "0")
        COLN("v[84:87]", "v84", "v85", "v86", "v87", "v30", "v28", "0x400")
        COLN("v[88:91]", "v88", "v89", "v90", "v91", "v28", "v30", "0x800")
        COLN("v[92:95]", "v92", "v93", "v94", "v95", "v30", "v28", "0xC00")
        ADDVO
        STOREBLK("0x100")
        WAITG
        COLN("v[96:99]",   "v96",  "v97",  "v98",  "v99",  "v28", "v30", "0")
        COLN("v[100:103]", "v100", "v101", "v102", "v103", "v30", "v28", "0x400")
        COLN("v[104:107]", "v104", "v105", "v106", "v107", "v28", "v30", "0x800")
        COLN("v[108:111]", "v108", "v109", "v110", "v111", "v30", "v28", "0xC00")
        ADDVO
        COLN("v[112:115]", "v112", "v113", "v114", "v115", "v28", "v30", "0")
        COLN("v[116:119]", "v116", "v117", "v118", "v119", "v30", "v28", "0x400")
        COLN("v[120:123]", "v120", "v121", "v122", "v123", "v28", "v30", "0x800")
        COLN("v[124:127]", "v124", "v125", "v126", "v127", "v30", "v28", "0xC00")
        ADDVO
        STOREBLK("0x200")
        WAITG
        COLN("v[128:131]", "v128", "v129", "v130", "v131", "v28", "v30", "0")
        COLN("v[132:135]", "v132", "v133", "v134", "v135", "v30", "v28", "0x400")
        COLN("v[136:139]", "v136", "v137", "v138", "v139", "v28", "v30", "0x800")
        COLN("v[140:143]", "v140", "v141", "v142", "v143", "v30", "v28", "0xC00")
        ADDVO
        COLN("v[144:147]", "v144", "v145", "v146", "v147", "v28", "v30", "0")
        COLN("v[148:151]", "v148", "v149", "v150", "v151", "v30", "v28", "0x400")
        COLN("v[152:155]", "v152", "v153", "v154", "v155", "v28", "v30", "0x800")
        COLN("v[156:159]", "v156", "v157", "v158", "v159", "v30", "v28", "0xC00")
        ADDVO
        STOREBLK("0x300")
        "v_add_u32 %[df], 0x400, %[df]\n\t"
        "s_sub_u32 s26, s26, 1\n\t"
        "s_cmp_lg_u32 s26, 0\n\t"
        "s_cbranch_scc1 Lmas_%=\n\t"
        : [v0]"+v"(v0), [v1]"+v"(v1), [v2]"+v"(v2), [v3]"+v"(v3),
          [a0]"+v"(a0), [a1]"+v"(a1), [a2]"+v"(a2), [a3]"+v"(a3),
          [vo]"+v"(vo), [df]"+v"(df)
        : [sb]"s"(sb), [db]"s"(db)
        : "vcc", "scc", "memory",
          "s20","s21","s22","s23","s24","s25","s26",
          "v28","v29","v30",
          "v32","v33","v34","v35","v36","v37","v38","v39",
          "v40","v41","v42","v43","v44","v45","v46","v47",
          "v48","v49","v50","v51","v52","v53","v54","v55",
          "v56","v57","v58","v59","v60","v61","v62","v63",
          "v64","v65","v66","v67","v68","v69","v70","v71",
          "v72","v73","v74","v75","v76","v77","v78","v79",
          "v80","v81","v82","v83","v84","v85","v86","v87",
          "v88","v89","v90","v91","v92","v93","v94","v95",
          "v96","v97","v98","v99","v100","v101","v102","v103",
          "v104","v105","v106","v107","v108","v109","v110","v111",
          "v112","v113","v114","v115","v116","v117","v118","v119",
          "v120","v121","v122","v123","v124","v125","v126","v127",
          "v128","v129","v130","v131","v132","v133","v134","v135",
          "v136","v137","v138","v139","v140","v141","v142","v143",
          "v144","v145","v146","v147","v148","v149","v150","v151",
          "v152","v153","v154","v155","v156","v157","v158","v159");
    // tail loads (cols 2048..2079) overrun into the adjacent scratch region
    // (still in-bounds of the surrounding buffer) -> harmless.
}

// ---------------------------------------------------------------------------
// Kernel 2b: exit-table build + LEVEL-2 composition (verified R9).
// ---------------------------------------------------------------------------
__global__ __launch_bounds__(256) void mas_tab_kernel(
    const unsigned int* __restrict__ diag_g, unsigned char* __restrict__ E_g,
    unsigned char* __restrict__ E2_g)
{
    __shared__ unsigned char El[16][256];
    const int t  = threadIdx.x;        // entry row
    const int cg = blockIdx.x;         // chunk group of 16
    const int b  = blockIdx.y;
    const unsigned int* dg = diag_g + (size_t)b * (TY_ / 8) * 64;
    unsigned char* Eb = E_g + (size_t)b * (TY_ / 8) * 256;
    const int p = t >> 3;

    for (int k = 0; k < 16; ++k) {
        const int c = cg * 16 + k;
        unsigned long long W  = *(const unsigned long long*)&dg[c * 64 + 2 * p];
        unsigned long long Wl = p > 0
            ? *(const unsigned long long*)&dg[c * 64 + 2 * (p - 1)] : 0ULL;
        int ii = t;
#pragma unroll
        for (int jb = 7; jb >= 0; --jb) BT_STEP(jb)
        Eb[c * 256 + t] = (unsigned char)ii;
        El[k][t] = (unsigned char)ii;
    }
    __syncthreads();
    int ii = t;
#pragma unroll
    for (int k = 15; k >= 0; --k) ii = El[k][ii];
    E2_g[((size_t)b * 16 + cg) * 256 + t] = (unsigned char)ii;
}

// ---------------------------------------------------------------------------
// Kernel 2c: MAS backtrace via 2-LEVEL exit tables (verified R9).
// ---------------------------------------------------------------------------
__global__ __launch_bounds__(256) void mas_bt_kernel(
    const unsigned int* __restrict__ diag_g, const unsigned char* __restrict__ E_g,
    const unsigned char* __restrict__ E2_g,
    const int* __restrict__ xlen, const int* __restrict__ ylen,
    float* __restrict__ dr_out, int* __restrict__ idx_out)
{
    __shared__ unsigned char E[256 * 256];      // 64 KiB
    __shared__ unsigned char E2l[16 * 256];     // 4 KiB
    __shared__ unsigned char entry_s[256];
    __shared__ unsigned char cg_entry[16];
    __shared__ int rows_l[TY_];                 // 8 KiB
    __shared__ int cnt_l[TX_];                  // 1 KiB
    const int tid = threadIdx.x;
    const int b = blockIdx.x;
    const int x_len = xlen[b];
    const int y_len = ylen[b];

    cnt_l[tid] = 0;

    const uint4* srcE = (const uint4*)(E_g + (size_t)b * (TY_ / 8) * 256);
    uint4* dstE = (uint4*)E;
#pragma unroll
    for (int it = 0; it < 16; ++it)
        dstE[tid + it * 256] = srcE[tid + it * 256];
    const uint4* srcE2 = (const uint4*)(E2_g + (size_t)b * 16 * 256);
    ((uint4*)E2l)[tid] = srcE2[tid];            // 4 KiB
    __syncthreads();

    const unsigned int* dg = diag_g + (size_t)b * (TY_ / 8) * 64;
    int* ib = idx_out + (size_t)b * TY_;
    const int jc = (y_len - 1) >> 3;            // partial chunk index
    const int cg0 = jc >> 4;                    // cg containing partial chunk

    if (tid == 0) {
        int ii = x_len - 1;
        int p = ii >> 3;
        unsigned long long W  = *(const unsigned long long*)&dg[jc * 64 + 2 * p];
        unsigned long long Wl = p > 0
            ? *(const unsigned long long*)&dg[jc * 64 + 2 * (p - 1)] : 0ULL;
        for (int jb = (y_len - 1) & 7; jb >= 0; --jb) {
            int j = 8 * jc + jb;
            ib[j] = ii; rows_l[j] = ii;
            BT_STEP(jb)
        }
        int cur = ii;
        for (int c = jc - 1; c >= cg0 * 16; --c) {
            entry_s[c] = (unsigned char)cur;
            cur = E[c * 256 + cur];
        }
        for (int cg = cg0 - 1; cg >= 0; --cg) {
            cg_entry[cg] = (unsigned char)cur;
            cur = E2l[cg * 256 + cur];
        }
    }
    __syncthreads();

    if (tid < cg0) {
        int cur = cg_entry[tid];
        for (int k = 15; k >= 0; --k) {
            int c = tid * 16 + k;
            entry_s[c] = (unsigned char)cur;
            cur = E[c * 256 + cur];
        }
    }
    __syncthreads();

    if (tid < jc) {
        const int c = tid;
        int ii = entry_s[c];
        int p = ii >> 3;
        unsigned long long W  = *(const unsigned long long*)&dg[c * 64 + 2 * p];
        unsigned long long Wl = p > 0
            ? *(const unsigned long long*)&dg[c * 64 + 2 * (p - 1)] : 0ULL;
        int r[8];
#pragma unroll
        for (int jb = 7; jb >= 0; --jb) {
            r[jb] = ii;
            BT_STEP(jb)
        }
        *reinterpret_cast<int4*>(&ib[8 * c])     = make_int4(r[0], r[1], r[2], r[3]);
        *reinterpret_cast<int4*>(&ib[8 * c + 4]) = make_int4(r[4], r[5], r[6], r[7]);
        *reinterpret_cast<int4*>(&rows_l[8 * c])     = make_int4(r[0], r[1], r[2], r[3]);
        *reinterpret_cast<int4*>(&rows_l[8 * c + 4]) = make_int4(r[4], r[5], r[6], r[7]);
    }
    __syncthreads();

    for (int t = tid; t < TY_; t += 256)
        if (t < y_len) atomicAdd(&cnt_l[rows_l[t]], 1);
    __syncthreads();
    dr_out[(size_t)b * TX_ + tid] = (float)cnt_l[tid];
}

// ---------------------------------------------------------------------------
// Kernel 3a: legacy dense emit (verified).
// ---------------------------------------------------------------------------
__global__ __launch_bounds__(256) void emit_kernel(
    const float* __restrict__ en, const int* __restrict__ ylen,
    const int* __restrict__ idx_in, float* __restrict__ o_en,
    float* __restrict__ attn)
{
    const int tid = threadIdx.x;
    const int b = blockIdx.x;
    const int r = blockIdx.y;
    const int y_len = ylen[b];
    const int* ib = idx_in + (size_t)b * TY_;

    if (r < 256) {
        const int x = r;
        float* out = attn + ((size_t)b * TX_ + x) * TY_;
        for (int t = tid; t < TY_; t += 256) {
            int ii = ib[t];
            out[t] = (t < y_len && ii == x) ? 1.f : 0.f;
        }
    } else {
        const int h = r - 256;
        __shared__ float enr[256];
        enr[tid] = en[((size_t)b * H_ + h) * TX_ + tid];
        __syncthreads();
        float* out = o_en + ((size_t)b * H_ + h) * TY_;
        for (int t = tid; t < TY_; t += 256) {
            int ii = ib[t];
            bool a = (t < y_len);
            int is = a ? ii : 0;
            out[t] = a ? enr[is] : 0.f;
        }
    }
}

// ---------------------------------------------------------------------------
// Kernel 3b: sparse emit (verified R8/R9) — ws path, attn stays memset-zero.
// ---------------------------------------------------------------------------
__global__ __launch_bounds__(256) void emit_sparse_kernel(
    const float* __restrict__ en, const int* __restrict__ ylen,
    const int* __restrict__ idx_in, float* __restrict__ o_en,
    float* __restrict__ attn)
{
    const int tid = threadIdx.x;
    const int b = blockIdx.x;
    const int r = blockIdx.y;           // 0..255 = o_en rows, 256 = attn scatter
    const int y_len = ylen[b];
    const int* ib = idx_in + (size_t)b * TY_;

    if (r == 256) {
        float* ab = attn + (size_t)b * TX_ * TY_;
        for (int t = tid; t < TY_; t += 256)
            if (t < y_len) ab[(size_t)ib[t] * TY_ + t] = 1.f;
    } else {
        const int h = r;
        __shared__ float enr[256];
        enr[tid] = en[((size_t)b * H_ + h) * TX_ + tid];
        __syncthreads();
        float* out = o_en + ((size_t)b * H_ + h) * TY_;
        for (int t = tid; t < TY_; t += 256) {
            int ii = ib[t];
            bool a = (t < y_len);
            int is = a ? ii : 0;
            out[t] = a ? enr[is] : 0.f;
        }
    }
}

// ---------------------------------------------------------------------------
extern "C" void kernel_launch(void* const* d_in, const int* in_sizes, int n_in,
                              void* d_out, int out_size, void* d_ws, size_t ws_size,
                              hipStream_t stream)
{
    const float* en = (const float*)d_in[0];
    const float* mu = (const float*)d_in[1];
    const float* ls = (const float*)d_in[2];
    const float* y  = (const float*)d_in[3];
    const int* xl   = (const int*)d_in[4];
    const int* yl   = (const int*)d_in[5];

    float* o_en = (float*)d_out;                       // [16,256,2048]
    float* attn = o_en + (size_t)B_ * TX_ * TY_;       // [16,256,2048]
    float* dr   = attn + (size_t)B_ * TX_ * TY_;       // [16,256]
    float* logp = dr + (size_t)B_ * TX_;               // [16,256,2048]

    const size_t logp_t_bytes = (size_t)B_ * TX_ * TY_ * 4;      // 33.5 MB
    const size_t E_bytes      = (size_t)B_ * (TY_ / 8) * 256;    // 1 MB
    const size_t idx_bytes    = (size_t)B_ * TY_ * 4;            // 128 KB

    unsigned int* diag_g = (unsigned int*)o_en;        // diag scratch (1 MB)
    unsigned char* E2_g = (unsigned char*)o_en + (1u << 21);  // E2 (64 KB)

    float* logp_t;
    unsigned char* E_g;
    int* idxArr;
    bool sparse;
    if (ws_size >= logp_t_bytes + E_bytes + idx_bytes) {
        logp_t = (float*)d_ws;
        E_g    = (unsigned char*)d_ws + logp_t_bytes;
        idxArr = (int*)((char*)d_ws + logp_t_bytes + E_bytes);
        sparse = true;
    } else {
        logp_t = attn;
        E_g    = (unsigned char*)attn;
        idxArr = (int*)d_ws;
        sparse = false;
    }

    dim3 g1(2, 16, 16);
    logp_kernel<<<g1, 256, 0, stream>>>(mu, ls, y, logp_t);

    // 16 scan blocks + 256 shadow transpose-copy blocks (logp_t -> logp)
    mas_fwd_kernel<<<dim3(16 + 256), dim3(256), 0, stream>>>(logp_t, diag_g, logp);
    mas_tab_kernel<<<dim3(16, 16), dim3(256), 0, stream>>>(diag_g, E_g, E2_g);
    mas_bt_kernel<<<dim3(16), dim3(256), 0, stream>>>(diag_g, E_g, E2_g,
                                                      xl, yl, dr, idxArr);

    if (sparse) {
        dim3 g3(16, 257);
        emit_sparse_kernel<<<g3, 256, 0, stream>>>(en, yl, idxArr, o_en, attn);
    } else {
        dim3 g3(16, 512);
        emit_kernel<<<g3, 256, 0, stream>>>(en, yl, idxArr, o_en, attn);
    }
}

// Round 12
// 277.368 us; speedup vs baseline: 1.0103x; 1.0103x over previous
//
#include <hip/hip_runtime.h>
#include <hip/hip_bf16.h>
#include <cstdint>
#include <cstddef>

#define B_ 16
#define TX_ 256
#define TY_ 2048
#define C_ 80
#define H_ 256
#define NEG_ -1e9f
#define NEG_I (int)0xCE6E6B28   // bit pattern of -1e9f

// one backtrace step at column-in-chunk jb from row ii, using window pair W
// (rows 8p..8p+7) with fallback Wl (rows 8p-8..8p-1).
// Diag bit layout (4 independent carry-push chains in fwd): within each
// 32-bit word (4 rows), row r = byte r; column jb at bit (7-jb).
#define BT_STEP(JB)                                                           \
    {                                                                         \
        unsigned bit = ((unsigned)(W >> (((ii & 7) << 3)                      \
                                         | (7 - (JB)))) & 1u)                 \
                     & (unsigned)(ii > 0);                                    \
        ii -= (int)bit;                                                       \
        W = (bit && ((ii & 7) == 7)) ? Wl : W;                                \
    }

// ---------------------------------------------------------------------------
// Kernel 1: logp (verified). Writes BOTH logp_out and logp_t — R11 proved
// logp is compute-bound (removing the 33.5 MB logp_out write saved nothing).
// ---------------------------------------------------------------------------
__global__ __launch_bounds__(256) void logp_kernel(
    const float* __restrict__ mu, const float* __restrict__ ls,
    const float* __restrict__ y, float* __restrict__ logp_out,
    float* __restrict__ logp_t)
{
    __shared__ float2 coef[16 * 80];
    __shared__ float  aux[16 * 80];
    __shared__ float  Kx[16];
    __shared__ float  yt[16 * 1028];

    const int tid = threadIdx.x;
    const int t0 = blockIdx.x * 1024;
    const int x0 = blockIdx.y * 16;
    const int b  = blockIdx.z;

    for (int i = tid; i < 16 * 80; i += 256) {
        int c = i >> 4, x = i & 15;
        float m = mu[(size_t)(b * C_ + c) * TX_ + x0 + x];
        float l = ls[(size_t)(b * C_ + c) * TX_ + x0 + x];
        float w = __expf(-2.f * l);
        coef[x * 80 + c] = make_float2(w, -2.f * m * w);
        aux[x * 80 + c]  = fmaf(m * m, w, l);
    }
    __syncthreads();
    if (tid < 16) {
        float s = 0.f;
        for (int c = 0; c < C_; ++c) s += aux[tid * 80 + c];
        Kx[tid] = -0.5f * s / (float)C_;
    }

    float acc[16][4];
#pragma unroll
    for (int x = 0; x < 16; ++x)
#pragma unroll
        for (int r = 0; r < 4; ++r) acc[x][r] = 0.f;

    const float4* y4 = (const float4*)y;
    for (int c0 = 0; c0 < C_; c0 += 16) {
        __syncthreads();
        for (int it = 0; it < 16; ++it) {
            int f = tid + it * 256;
            int t = f >> 2, k = f & 3;
            float4 v = y4[(size_t)(b * TY_ + t0 + t) * 20 + (c0 >> 2) + k];
            yt[(4 * k + 0) * 1028 + t] = v.x;
            yt[(4 * k + 1) * 1028 + t] = v.y;
            yt[(4 * k + 2) * 1028 + t] = v.z;
            yt[(4 * k + 3) * 1028 + t] = v.w;
        }
        __syncthreads();
        for (int cl = 0; cl < 16; ++cl) {
            const float4 yv = *reinterpret_cast<const float4*>(&yt[cl * 1028 + 4 * tid]);
            float4 y2 = make_float4(yv.x * yv.x, yv.y * yv.y, yv.z * yv.z, yv.w * yv.w);
#pragma unroll
            for (int x = 0; x < 16; ++x) {
                float2 f2 = coef[x * 80 + c0 + cl];
                acc[x][0] = fmaf(y2.x, f2.x, fmaf(yv.x, f2.y, acc[x][0]));
                acc[x][1] = fmaf(y2.y, f2.x, fmaf(yv.y, f2.y, acc[x][1]));
                acc[x][2] = fmaf(y2.z, f2.x, fmaf(yv.z, f2.y, acc[x][2]));
                acc[x][3] = fmaf(y2.w, f2.x, fmaf(yv.w, f2.y, acc[x][3]));
            }
        }
    }

#pragma unroll
    for (int x = 0; x < 16; ++x) {
        float kx = Kx[x];
#pragma unroll
        for (int r = 0; r < 4; ++r) acc[x][r] = fmaf(acc[x][r], -0.5f / (float)C_, kx);
        float4 out = make_float4(acc[x][0], acc[x][1], acc[x][2], acc[x][3]);
        *reinterpret_cast<float4*>(
            &logp_out[(size_t)(b * TX_ + x0 + x) * TY_ + t0 + 4 * tid]) = out;
    }
#pragma unroll
    for (int r = 0; r < 4; ++r) {
#pragma unroll
        for (int q = 0; q < 4; ++q) {
            float4 out = make_float4(acc[4 * q + 0][r], acc[4 * q + 1][r],
                                     acc[4 * q + 2][r], acc[4 * q + 3][r]);
            *reinterpret_cast<float4*>(
                &logp_t[(size_t)(b * TY_ + t0 + 4 * tid + r) * TX_ + x0 + 4 * q]) = out;
        }
    }
}

// ---------------------------------------------------------------------------
// Kernel 2a: MAS forward — R4-VERIFIED full inline asm scan (single wave per
// batch, stall-free schedule, 32-col prefetch in v32..v159, vmcnt(24)).
// Issue-bound floor: 17 VALU + 1 VMEM per column.
// ---------------------------------------------------------------------------
#define PROQ(A, Bq, Cq, Dq) \
    "global_load_dwordx4 " A ", %[vo], %[sb]\n\t" \
    "global_load_dwordx4 " Bq ", %[vo], %[sb] offset:0x400\n\t" \
    "global_load_dwordx4 " Cq ", %[vo], %[sb] offset:0x800\n\t" \
    "global_load_dwordx4 " Dq ", %[vo], %[sb] offset:0xC00\n\t" \
    "v_add_u32 %[vo], 0x1000, %[vo]\n\t"

#define ADDVO "v_add_u32 %[vo], 0x1000, %[vo]\n\t"

// SHU: sh register for THIS column; SHD: sh register produced for NEXT column.
#define COLN(RQ, R0, R1, R2, R3, SHU, SHD, OFF) \
    "v_cmp_gt_f32 vcc, " SHU ", %[v0]\n\t" \
    "v_cmp_gt_f32 s[20:21], %[v0], %[v1]\n\t" \
    "v_cmp_gt_f32 s[22:23], %[v1], %[v2]\n\t" \
    "v_cmp_gt_f32 s[24:25], %[v2], %[v3]\n\t" \
    "v_max_f32 %[v3], %[v2], %[v3]\n\t" \
    "v_max_f32 %[v2], %[v1], %[v2]\n\t" \
    "v_add_f32 %[v3], " R3 ", %[v3]\n\t" \
    "v_max_f32 %[v1], %[v0], %[v1]\n\t" \
    "v_max_f32 %[v0], " SHU ", %[v0]\n\t" \
    "v_mov_b32_dpp " SHD ", %[v3] wave_shr:1 row_mask:0xf bank_mask:0xf\n\t" \
    "v_add_f32 %[v2], " R2 ", %[v2]\n\t" \
    "v_add_f32 %[v1], " R1 ", %[v1]\n\t" \
    "v_add_f32 %[v0], " R0 ", %[v0]\n\t" \
    "v_addc_co_u32 %[a0], vcc, %[a0], %[a0], vcc\n\t" \
    "v_addc_co_u32 %[a1], s[20:21], %[a1], %[a1], s[20:21]\n\t" \
    "v_addc_co_u32 %[a2], s[22:23], %[a2], %[a2], s[22:23]\n\t" \
    "v_addc_co_u32 %[a3], s[24:25], %[a3], %[a3], s[24:25]\n\t" \
    "global_load_dwordx4 " RQ ", %[vo], %[sb] offset:" OFF "\n\t"

#define STOREBLK(OFFD) \
    "v_lshl_or_b32 v29, %[a1], 8, %[a0]\n\t" \
    "v_lshl_or_b32 v29, %[a2], 16, v29\n\t" \
    "v_lshl_or_b32 v29, %[a3], 24, v29\n\t" \
    "global_store_dword %[df], v29, %[db] offset:" OFFD "\n\t" \
    "v_mov_b32 %[a0], 0\n\t" \
    "v_mov_b32 %[a1], 0\n\t" \
    "v_mov_b32 %[a2], 0\n\t" \
    "v_mov_b32 %[a3], 0\n\t"

#define WAITG "s_waitcnt vmcnt(24)\n\t"

__global__ __launch_bounds__(64, 1) void mas_fwd_kernel(
    const float* __restrict__ logp_t, unsigned int* __restrict__ diag_g)
{
    const int lane = threadIdx.x;
    const int b = blockIdx.x;

    uint64_t sb = (uint64_t)(logp_t + (size_t)b * TY_ * TX_);
    uint64_t db = (uint64_t)(diag_g + (size_t)b * (TY_ / 8) * 64);
    unsigned vo = (unsigned)(lane * 16);   // voffset into logp_t (bytes)
    unsigned df = (unsigned)(lane * 4);    // voffset into diag (bytes)

    float v0 = (lane == 0) ? 0.f : NEG_, v1 = NEG_, v2 = NEG_, v3 = NEG_;
    unsigned a0 = 0, a1 = 0, a2 = 0, a3 = 0;

    asm volatile(
        // ---- sh ping-pong init (all lanes NEG; lane0 persists NEG) ----
        "v_mov_b32 v28, 0xce6e6b28\n\t"
        "v_mov_b32 v30, 0xce6e6b28\n\t"
        // ---- 32-column prologue fill (cols 0..31) ----
        PROQ("v[32:35]",   "v[36:39]",   "v[40:43]",   "v[44:47]")
        PROQ("v[48:51]",   "v[52:55]",   "v[56:59]",   "v[60:63]")
        PROQ("v[64:67]",   "v[68:71]",   "v[72:75]",   "v[76:79]")
        PROQ("v[80:83]",   "v[84:87]",   "v[88:91]",   "v[92:95]")
        PROQ("v[96:99]",   "v[100:103]", "v[104:107]", "v[108:111]")
        PROQ("v[112:115]", "v[116:119]", "v[120:123]", "v[124:127]")
        PROQ("v[128:131]", "v[132:135]", "v[136:139]", "v[140:143]")
        PROQ("v[144:147]", "v[148:151]", "v[152:155]", "v[156:159]")
        "s_mov_b32 s26, 64\n\t"
        "Lmas_%=:\n\t"
        // ---- group 0: cols +0..7 (buffer v32..v63) ----
        WAITG
        COLN("v[32:35]", "v32", "v33", "v34", "v35", "v28", "v30", "0")
        COLN("v[36:39]", "v36", "v37", "v38", "v39", "v30", "v28", "0x400")
        COLN("v[40:43]", "v40", "v41", "v42", "v43", "v28", "v30", "0x800")
        COLN("v[44:47]", "v44", "v45", "v46", "v47", "v30", "v28", "0xC00")
        ADDVO
        COLN("v[48:51]", "v48", "v49", "v50", "v51", "v28", "v30", "0")
        COLN("v[52:55]", "v52", "v53", "v54", "v55", "v30", "v28", "0x400")
        COLN("v[56:59]", "v56", "v57", "v58", "v59", "v28", "v30", "0x800")
        COLN("v[60:63]", "v60", "v61", "v62", "v63", "v30", "v28", "0xC00")
        ADDVO
        STOREBLK("0")
        // ---- group 1: cols +8..15 (v64..v95) ----
        WAITG
        COLN("v[64:67]", "v64", "v65", "v66", "v67", "v28", "v30", "0")
        COLN("v[68:71]", "v68", "v69", "v70", "v71", "v30", "v28", "0x400")
        COLN("v[72:75]", "v72", "v73", "v74", "v75", "v28", "v30", "0x800")
        COLN("v[76:79]", "v76", "v77", "v78", "v79", "v30", "v28", "0xC00")
        ADDVO
        COLN("v[80:83]", "v80", "v81", "v82", "v83", "v28", "v30", "0")
        COLN("v[84:87]", "v84", "v85", "v86", "v87", "v30", "v28", "0x400")
        COLN("v[88:91]", "v88", "v89", "v90", "v91", "v28", "v30", "0x800")
        COLN("v[92:95]", "v92", "v93", "v94", "v95", "v30", "v28", "0xC00")
        ADDVO
        STOREBLK("0x100")
        // ---- group 2: cols +16..23 (v96..v127) ----
        WAITG
        COLN("v[96:99]",   "v96",  "v97",  "v98",  "v99",  "v28", "v30", "0")
        COLN("v[100:103]", "v100", "v101", "v102", "v103", "v30", "v28", "0x400")
        COLN("v[104:107]", "v104", "v105", "v106", "v107", "v28", "v30", "0x800")
        COLN("v[108:111]", "v108", "v109", "v110", "v111", "v30", "v28", "0xC00")
        ADDVO
        COLN("v[112:115]", "v112", "v113", "v114", "v115", "v28", "v30", "0")
        COLN("v[116:119]", "v116", "v117", "v118", "v119", "v30", "v28", "0x400")
        COLN("v[120:123]", "v120", "v121", "v122", "v123", "v28", "v30", "0x800")
        COLN("v[124:127]", "v124", "v125", "v126", "v127", "v30", "v28", "0xC00")
        ADDVO
        STOREBLK("0x200")
        // ---- group 3: cols +24..31 (v128..v159) ----
        WAITG
        COLN("v[128:131]", "v128", "v129", "v130", "v131", "v28", "v30", "0")
        COLN("v[132:135]", "v132", "v133", "v134", "v135", "v30", "v28", "0x400")
        COLN("v[136:139]", "v136", "v137", "v138", "v139", "v28", "v30", "0x800")
        COLN("v[140:143]", "v140", "v141", "v142", "v143", "v30", "v28", "0xC00")
        ADDVO
        COLN("v[144:147]", "v144", "v145", "v146", "v147", "v28", "v30", "0")
        COLN("v[148:151]", "v148", "v149", "v150", "v151", "v30", "v28", "0x400")
        COLN("v[152:155]", "v152", "v153", "v154", "v155", "v28", "v30", "0x800")
        COLN("v[156:159]", "v156", "v157", "v158", "v159", "v30", "v28", "0xC00")
        ADDVO
        STOREBLK("0x300")
        "v_add_u32 %[df], 0x400, %[df]\n\t"
        "s_sub_u32 s26, s26, 1\n\t"
        "s_cmp_lg_u32 s26, 0\n\t"
        "s_cbranch_scc1 Lmas_%=\n\t"
        : [v0]"+v"(v0), [v1]"+v"(v1), [v2]"+v"(v2), [v3]"+v"(v3),
          [a0]"+v"(a0), [a1]"+v"(a1), [a2]"+v"(a2), [a3]"+v"(a3),
          [vo]"+v"(vo), [df]"+v"(df)
        : [sb]"s"(sb), [db]"s"(db)
        : "vcc", "scc", "memory",
          "s20","s21","s22","s23","s24","s25","s26",
          "v28","v29","v30",
          "v32","v33","v34","v35","v36","v37","v38","v39",
          "v40","v41","v42","v43","v44","v45","v46","v47",
          "v48","v49","v50","v51","v52","v53","v54","v55",
          "v56","v57","v58","v59","v60","v61","v62","v63",
          "v64","v65","v66","v67","v68","v69","v70","v71",
          "v72","v73","v74","v75","v76","v77","v78","v79",
          "v80","v81","v82","v83","v84","v85","v86","v87",
          "v88","v89","v90","v91","v92","v93","v94","v95",
          "v96","v97","v98","v99","v100","v101","v102","v103",
          "v104","v105","v106","v107","v108","v109","v110","v111",
          "v112","v113","v114","v115","v116","v117","v118","v119",
          "v120","v121","v122","v123","v124","v125","v126","v127",
          "v128","v129","v130","v131","v132","v133","v134","v135",
          "v136","v137","v138","v139","v140","v141","v142","v143",
          "v144","v145","v146","v147","v148","v149","v150","v151",
          "v152","v153","v154","v155","v156","v157","v158","v159");
    // NOTE: tail loads (cols 2048..2079) read past this batch's logp_t rows;
    // that memory is still inside the surrounding buffer -> harmless.
}

// ---------------------------------------------------------------------------
// Kernel 2b: exit-table build + LEVEL-2 composition (verified R9).
// ---------------------------------------------------------------------------
__global__ __launch_bounds__(256) void mas_tab_kernel(
    const unsigned int* __restrict__ diag_g, unsigned char* __restrict__ E_g,
    unsigned char* __restrict__ E2_g)
{
    __shared__ unsigned char El[16][256];
    const int t  = threadIdx.x;        // entry row
    const int cg = blockIdx.x;         // chunk group of 16
    const int b  = blockIdx.y;
    const unsigned int* dg = diag_g + (size_t)b * (TY_ / 8) * 64;
    unsigned char* Eb = E_g + (size_t)b * (TY_ / 8) * 256;
    const int p = t >> 3;

    for (int k = 0; k < 16; ++k) {
        const int c = cg * 16 + k;
        unsigned long long W  = *(const unsigned long long*)&dg[c * 64 + 2 * p];
        unsigned long long Wl = p > 0
            ? *(const unsigned long long*)&dg[c * 64 + 2 * (p - 1)] : 0ULL;
        int ii = t;
#pragma unroll
        for (int jb = 7; jb >= 0; --jb) BT_STEP(jb)
        Eb[c * 256 + t] = (unsigned char)ii;
        El[k][t] = (unsigned char)ii;
    }
    __syncthreads();
    int ii = t;
#pragma unroll
    for (int k = 15; k >= 0; --k) ii = El[k][ii];
    E2_g[((size_t)b * 16 + cg) * 256 + t] = (unsigned char)ii;
}

// ---------------------------------------------------------------------------
// Kernel 2c: MAS backtrace via 2-LEVEL exit tables (verified R9).
// ---------------------------------------------------------------------------
__global__ __launch_bounds__(256) void mas_bt_kernel(
    const unsigned int* __restrict__ diag_g, const unsigned char* __restrict__ E_g,
    const unsigned char* __restrict__ E2_g,
    const int* __restrict__ xlen, const int* __restrict__ ylen,
    float* __restrict__ dr_out, int* __restrict__ idx_out)
{
    __shared__ unsigned char E[256 * 256];      // 64 KiB
    __shared__ unsigned char E2l[16 * 256];     // 4 KiB
    __shared__ unsigned char entry_s[256];
    __shared__ unsigned char cg_entry[16];
    __shared__ int rows_l[TY_];                 // 8 KiB
    __shared__ int cnt_l[TX_];                  // 1 KiB
    const int tid = threadIdx.x;
    const int b = blockIdx.x;
    const int x_len = xlen[b];
    const int y_len = ylen[b];

    cnt_l[tid] = 0;

    const uint4* srcE = (const uint4*)(E_g + (size_t)b * (TY_ / 8) * 256);
    uint4* dstE = (uint4*)E;
#pragma unroll
    for (int it = 0; it < 16; ++it)
        dstE[tid + it * 256] = srcE[tid + it * 256];
    const uint4* srcE2 = (const uint4*)(E2_g + (size_t)b * 16 * 256);
    ((uint4*)E2l)[tid] = srcE2[tid];            // 4 KiB
    __syncthreads();

    const unsigned int* dg = diag_g + (size_t)b * (TY_ / 8) * 64;
    int* ib = idx_out + (size_t)b * TY_;
    const int jc = (y_len - 1) >> 3;            // partial chunk index
    const int cg0 = jc >> 4;                    // cg containing partial chunk

    if (tid == 0) {
        int ii = x_len - 1;
        int p = ii >> 3;
        unsigned long long W  = *(const unsigned long long*)&dg[jc * 64 + 2 * p];
        unsigned long long Wl = p > 0
            ? *(const unsigned long long*)&dg[jc * 64 + 2 * (p - 1)] : 0ULL;
        for (int jb = (y_len - 1) & 7; jb >= 0; --jb) {
            int j = 8 * jc + jb;
            ib[j] = ii; rows_l[j] = ii;
            BT_STEP(jb)
        }
        int cur = ii;
        for (int c = jc - 1; c >= cg0 * 16; --c) {
            entry_s[c] = (unsigned char)cur;
            cur = E[c * 256 + cur];
        }
        for (int cg = cg0 - 1; cg >= 0; --cg) {
            cg_entry[cg] = (unsigned char)cur;
            cur = E2l[cg * 256 + cur];
        }
    }
    __syncthreads();

    if (tid < cg0) {
        int cur = cg_entry[tid];
        for (int k = 15; k >= 0; --k) {
            int c = tid * 16 + k;
            entry_s[c] = (unsigned char)cur;
            cur = E[c * 256 + cur];
        }
    }
    __syncthreads();

    if (tid < jc) {
        const int c = tid;
        int ii = entry_s[c];
        int p = ii >> 3;
        unsigned long long W  = *(const unsigned long long*)&dg[c * 64 + 2 * p];
        unsigned long long Wl = p > 0
            ? *(const unsigned long long*)&dg[c * 64 + 2 * (p - 1)] : 0ULL;
        int r[8];
#pragma unroll
        for (int jb = 7; jb >= 0; --jb) {
            r[jb] = ii;
            BT_STEP(jb)
        }
        *reinterpret_cast<int4*>(&ib[8 * c])     = make_int4(r[0], r[1], r[2], r[3]);
        *reinterpret_cast<int4*>(&ib[8 * c + 4]) = make_int4(r[4], r[5], r[6], r[7]);
        *reinterpret_cast<int4*>(&rows_l[8 * c])     = make_int4(r[0], r[1], r[2], r[3]);
        *reinterpret_cast<int4*>(&rows_l[8 * c + 4]) = make_int4(r[4], r[5], r[6], r[7]);
    }
    __syncthreads();

    for (int t = tid; t < TY_; t += 256)
        if (t < y_len) atomicAdd(&cnt_l[rows_l[t]], 1);
    __syncthreads();
    dr_out[(size_t)b * TX_ + tid] = (float)cnt_l[tid];
}

// ---------------------------------------------------------------------------
// Kernel 3a: legacy dense emit (verified).
// ---------------------------------------------------------------------------
__global__ __launch_bounds__(256) void emit_kernel(
    const float* __restrict__ en, const int* __restrict__ ylen,
    const int* __restrict__ idx_in, float* __restrict__ o_en,
    float* __restrict__ attn)
{
    const int tid = threadIdx.x;
    const int b = blockIdx.x;
    const int r = blockIdx.y;
    const int y_len = ylen[b];
    const int* ib = idx_in + (size_t)b * TY_;

    if (r < 256) {
        const int x = r;
        float* out = attn + ((size_t)b * TX_ + x) * TY_;
        for (int t = tid; t < TY_; t += 256) {
            int ii = ib[t];
            out[t] = (t < y_len && ii == x) ? 1.f : 0.f;
        }
    } else {
        const int h = r - 256;
        __shared__ float enr[256];
        enr[tid] = en[((size_t)b * H_ + h) * TX_ + tid];
        __syncthreads();
        float* out = o_en + ((size_t)b * H_ + h) * TY_;
        for (int t = tid; t < TY_; t += 256) {
            int ii = ib[t];
            bool a = (t < y_len);
            int is = a ? ii : 0;
            out[t] = a ? enr[is] : 0.f;
        }
    }
}

// ---------------------------------------------------------------------------
// Kernel 3b: sparse emit (verified R8/R9) — ws path, attn stays memset-zero.
// ---------------------------------------------------------------------------
__global__ __launch_bounds__(256) void emit_sparse_kernel(
    const float* __restrict__ en, const int* __restrict__ ylen,
    const int* __restrict__ idx_in, float* __restrict__ o_en,
    float* __restrict__ attn)
{
    const int tid = threadIdx.x;
    const int b = blockIdx.x;
    const int r = blockIdx.y;           // 0..255 = o_en rows, 256 = attn scatter
    const int y_len = ylen[b];
    const int* ib = idx_in + (size_t)b * TY_;

    if (r == 256) {
        float* ab = attn + (size_t)b * TX_ * TY_;
        for (int t = tid; t < TY_; t += 256)
            if (t < y_len) ab[(size_t)ib[t] * TY_ + t] = 1.f;
    } else {
        const int h = r;
        __shared__ float enr[256];
        enr[tid] = en[((size_t)b * H_ + h) * TX_ + tid];
        __syncthreads();
        float* out = o_en + ((size_t)b * H_ + h) * TY_;
        for (int t = tid; t < TY_; t += 256) {
            int ii = ib[t];
            bool a = (t < y_len);
            int is = a ? ii : 0;
            out[t] = a ? enr[is] : 0.f;
        }
    }
}

// ---------------------------------------------------------------------------
extern "C" void kernel_launch(void* const* d_in, const int* in_sizes, int n_in,
                              void* d_out, int out_size, void* d_ws, size_t ws_size,
                              hipStream_t stream)
{
    const float* en = (const float*)d_in[0];
    const float* mu = (const float*)d_in[1];
    const float* ls = (const float*)d_in[2];
    const float* y  = (const float*)d_in[3];
    const int* xl   = (const int*)d_in[4];
    const int* yl   = (const int*)d_in[5];

    float* o_en = (float*)d_out;                       // [16,256,2048]
    float* attn = o_en + (size_t)B_ * TX_ * TY_;       // [16,256,2048]
    float* dr   = attn + (size_t)B_ * TX_ * TY_;       // [16,256]
    float* logp = dr + (size_t)B_ * TX_;               // [16,256,2048]

    const size_t logp_t_bytes = (size_t)B_ * TX_ * TY_ * 4;      // 33.5 MB
    const size_t E_bytes      = (size_t)B_ * (TY_ / 8) * 256;    // 1 MB
    const size_t idx_bytes    = (size_t)B_ * TY_ * 4;            // 128 KB

    unsigned int* diag_g = (unsigned int*)o_en;        // diag scratch (1 MB)
    unsigned char* E2_g = (unsigned char*)o_en + (1u << 21);  // E2 (64 KB)

    float* logp_t;
    unsigned char* E_g;
    int* idxArr;
    bool sparse;
    if (ws_size >= logp_t_bytes + E_bytes + idx_bytes) {
        logp_t = (float*)d_ws;
        E_g    = (unsigned char*)d_ws + logp_t_bytes;
        idxArr = (int*)((char*)d_ws + logp_t_bytes + E_bytes);
        sparse = true;
    } else {
        logp_t = attn;
        E_g    = (unsigned char*)attn;
        idxArr = (int*)d_ws;
        sparse = false;
    }

    dim3 g1(2, 16, 16);
    logp_kernel<<<g1, 256, 0, stream>>>(mu, ls, y, logp, logp_t);

    mas_fwd_kernel<<<dim3(16), dim3(64), 0, stream>>>(logp_t, diag_g);
    mas_tab_kernel<<<dim3(16, 16), dim3(256), 0, stream>>>(diag_g, E_g, E2_g);
    mas_bt_kernel<<<dim3(16), dim3(256), 0, stream>>>(diag_g, E_g, E2_g,
                                                      xl, yl, dr, idxArr);

    if (sparse) {
        dim3 g3(16, 257);
        emit_sparse_kernel<<<g3, 256, 0, stream>>>(en, yl, idxArr, o_en, attn);
    } else {
        dim3 g3(16, 512);
        emit_kernel<<<g3, 256, 0, stream>>>(en, yl, idxArr, o_en, attn);
    }
}